// Round 11
// baseline (210.654 us; speedup 1.0000x reference)
//
#include <hip/hip_runtime.h>
#include <math.h>

typedef __attribute__((ext_vector_type(8))) short short8;
typedef __attribute__((ext_vector_type(4))) float f32x4;
typedef __attribute__((ext_vector_type(16))) float f32x16;

#define PSTRIDE 4160          // partials row stride in floats (non-pow2)

// round-to-nearest-even fp32 -> bf16 bits (validated numerics, keep exact)
__device__ __forceinline__ unsigned int bf16_rn(float x) {
    unsigned int u = __float_as_uint(x);
    return (u + 0x7FFFu + ((u >> 16) & 1u)) >> 16;
}

__device__ __forceinline__ short8 cvt8(float4 a, float4 b) {
    short8 h;
    h[0] = (short)bf16_rn(a.x); h[1] = (short)bf16_rn(a.y);
    h[2] = (short)bf16_rn(a.z); h[3] = (short)bf16_rn(a.w);
    h[4] = (short)bf16_rn(b.x); h[5] = (short)bf16_rn(b.y);
    h[6] = (short)bf16_rn(b.z); h[7] = (short)bf16_rn(b.w);
    return h;
}

// ---------------------------------------------------------------------------
// Kernel 1 (gram + CE fused): 512 threads (8 waves).
// CE blocks first (blk < ceCount). Gram: one block per (feature, 512-k
// chunk); grid = 3*128 + 4*64 = 640 + 64 CE.
// R11: LINE-DENSE loads. Cross-round law: per-CU delivery capped ~19 GB/s
// for scattered loads (32 lines/instr: R4 19, R6/R8 12, R10 5.3 GB/s/CU)
// regardless of depth/occupancy/asm batching; only line-dense kernels
// (repack, m13 copy) ever hit ~5 TB/s. So: stage via global_load_lds DMA
// (base + lane*16 = contiguous 1 KB/instr), double-buffered 2x32 KB LDS
// (4 sub-rounds of 128-k fp32), issue-early schedule (stage sr+1 before
// compute sr -> HBM latency hides under compute; R2's drain-serialized
// version validated the DMA+source-swizzle correctness).
// Source pre-swizzled per rule #21: global byte o of row r lands at LDS
// o ^ ((r&31)<<4) within the row's 512-B segment; fragment reads apply the
// same XOR -> 64 lanes hit each 16-B slot exactly 2x (2-way = free).
// Per sub-round each wave computes ONE k=16 step with the validated 3-acc
// trick (aOD += fa x fb, aD0 += fa x fa, aD1 += fb x fb; amplification 1.0x;
// R9-validated absmax 0). Cross-wave reduce + mirrored write-out = R9 code.
// ---------------------------------------------------------------------------
__global__ __launch_bounds__(512, 2) void gram_ce_kernel(
    const float* __restrict__ A, const float* __restrict__ B,
    float* __restrict__ partials, int nfA, int nfB,
    const float* __restrict__ logits, const int* __restrict__ target,
    float* __restrict__ out_copy, float* __restrict__ ce_rows, int ceCount)
{
    __shared__ float smem[16384];  // 64 KB: buf0 @0, buf1 @8192; reduce overlay
    const int t = threadIdx.x;

    if ((int)blockIdx.x < ceCount) {
        // ------------------ CE block ------------------
        const int row = blockIdx.x;
        const float* x = logits + row * 1000;
        float m = -INFINITY;
        for (int i = t; i < 1000; i += 512) {
            float v = x[i];
            out_copy[row * 1000 + i] = v;
            m = fmaxf(m, v);
        }
        smem[t] = m; __syncthreads();
        for (int s = 256; s > 0; s >>= 1) {
            if (t < s) smem[t] = fmaxf(smem[t], smem[t + s]);
            __syncthreads();
        }
        m = smem[0];
        __syncthreads();
        float ssum = 0.f;
        for (int i = t; i < 1000; i += 512) ssum += expf(x[i] - m);
        smem[t] = ssum; __syncthreads();
        for (int s = 256; s > 0; s >>= 1) {
            if (t < s) smem[t] += smem[t + s];
            __syncthreads();
        }
        if (t == 0) {
            double lse = (double)m + log((double)smem[0]);
            int tg = target[row];
            ce_rows[row] = (float)(-((double)x[tg] - lse));
        }
        return;
    }

    // ------------------ gram block ------------------
    const int gb = blockIdx.x - ceCount;
    const int uA = nfA * 128;              // A chunk-blocks (128 x 512k /feat)
    const float* xf;
    int c, D;
    if (gb < uA) {
        int f = gb >> 7; c = gb & 127; D = 65536;
        xf = A + (size_t)f * 64 * 65536;
    } else {
        int v = gb - uA;
        int f = v >> 6; c = v & 63; D = 32768;
        xf = B + (size_t)f * 64 * 32768;
    }

    const int wave = t >> 6, lane = t & 63;
    const int lr = lane & 31, hi = lane >> 5;

    // ---- per-lane pre-swizzled source pointers (4 row-pairs per wave) ----
    // pair p covers rows 2p,2p+1; lanes 0-31 -> row 2p, 32-63 -> row 2p+1.
    const char* Xc = (const char*)xf;
    const size_t cOff = (size_t)c * 2048;          // chunk byte offset in row
    const int g = lane * 16;
    const int rsel = g >> 9;                       // 0 or 1 within pair
    const int oswz0 = (g & 511);
    const char *src0, *src1, *src2, *src3;
    {
        int p0 = wave * 4;
        int r0 = 2 * p0 + rsel;
        int r1 = 2 * (p0 + 1) + rsel;
        int r2 = 2 * (p0 + 2) + rsel;
        int r3 = 2 * (p0 + 3) + rsel;
        src0 = Xc + (size_t)r0 * D * 4 + cOff + (oswz0 ^ ((r0 & 31) << 4));
        src1 = Xc + (size_t)r1 * D * 4 + cOff + (oswz0 ^ ((r1 & 31) << 4));
        src2 = Xc + (size_t)r2 * D * 4 + cOff + (oswz0 ^ ((r2 & 31) << 4));
        src3 = Xc + (size_t)r3 * D * 4 + cOff + (oswz0 ^ ((r3 & 31) << 4));
    }
    float* buf0 = smem;
    float* buf1 = smem + 8192;
    const int pbase = wave * 4;

#define STAGE4(dst, srOff)                                                   \
    do {                                                                     \
        __builtin_amdgcn_global_load_lds(                                    \
            (const __attribute__((address_space(1))) void*)(src0 + (srOff)), \
            (__attribute__((address_space(3))) void*)&(dst)[(pbase + 0) * 256], 16, 0, 0); \
        __builtin_amdgcn_global_load_lds(                                    \
            (const __attribute__((address_space(1))) void*)(src1 + (srOff)), \
            (__attribute__((address_space(3))) void*)&(dst)[(pbase + 1) * 256], 16, 0, 0); \
        __builtin_amdgcn_global_load_lds(                                    \
            (const __attribute__((address_space(1))) void*)(src2 + (srOff)), \
            (__attribute__((address_space(3))) void*)&(dst)[(pbase + 2) * 256], 16, 0, 0); \
        __builtin_amdgcn_global_load_lds(                                    \
            (const __attribute__((address_space(1))) void*)(src3 + (srOff)), \
            (__attribute__((address_space(3))) void*)&(dst)[(pbase + 3) * 256], 16, 0, 0); \
    } while (0)

    // prologue: stage sub-round 0
    STAGE4(buf0, 0);
    asm volatile("s_waitcnt vmcnt(0)" ::: "memory");
    __syncthreads();

    f32x16 aOD = (f32x16)0.f;
    f32x16 aD0 = (f32x16)0.f;
    f32x16 aD1 = (f32x16)0.f;

    const int fbase = wave * 64 + hi * 32;   // fragment byte base within row
    const int sa = lr << 4;                  // read-side swizzle

#pragma unroll
    for (int sr = 0; sr < 4; ++sr) {
        float* cur = (sr & 1) ? buf1 : buf0;
        float* nxt = (sr & 1) ? buf0 : buf1;
        if (sr < 3) STAGE4(nxt, (sr + 1) * 512);   // issue early, hide latency

        const char* cb = (const char*)cur;
        const int rowA = lr * 512, rowB = (32 + lr) * 512;
        float4 a0 = *(const float4*)(cb + rowA + ((fbase) ^ sa));
        float4 a1 = *(const float4*)(cb + rowA + ((fbase + 16) ^ sa));
        float4 b0 = *(const float4*)(cb + rowB + ((fbase) ^ sa));
        float4 b1 = *(const float4*)(cb + rowB + ((fbase + 16) ^ sa));
        short8 fa = cvt8(a0, a1);
        short8 fb = cvt8(b0, b1);
        aOD = __builtin_amdgcn_mfma_f32_32x32x16_bf16(fa, fb, aOD, 0, 0, 0);
        aD0 = __builtin_amdgcn_mfma_f32_32x32x16_bf16(fa, fa, aD0, 0, 0, 0);
        aD1 = __builtin_amdgcn_mfma_f32_32x32x16_bf16(fb, fb, aD1, 0, 0, 0);

        asm volatile("s_waitcnt vmcnt(0)" ::: "memory");
        __syncthreads();   // next buffer fully landed; safe to read/overwrite
    }
#undef STAGE4

    // ---- cross-wave reduce: d0 @0, d1 @1056, od @2112 (stride 33) ----
    // C layout: col = lane&31, row = (r&3)+8*(r>>2)+4*(lane>>5)  [m74/m101]
    if (wave == 0) {
#pragma unroll
        for (int r = 0; r < 16; ++r) {
            int rl = ((r & 3) + 8 * (r >> 2) + 4 * hi) * 33 + lr;
            smem[rl] = aD0[r];
            smem[1056 + rl] = aD1[r];
            smem[2112 + rl] = aOD[r];
        }
    }
    __syncthreads();
    if (wave != 0) {
#pragma unroll
        for (int r = 0; r < 16; ++r) {
            int rl = ((r & 3) + 8 * (r >> 2) + 4 * hi) * 33 + lr;
            atomicAdd(&smem[rl], aD0[r]);
            atomicAdd(&smem[1056 + rl], aD1[r]);
            atomicAdd(&smem[2112 + rl], aOD[r]);
        }
    }
    __syncthreads();

    // ---- write 64x64 partials, mirroring od for the lower-left quadrant ----
    float* outp = partials + (size_t)gb * PSTRIDE;
    for (int e = t; e < 4096; e += 512) {
        int rr = e >> 6, cc = e & 63;
        float v;
        if (rr < 32)
            v = (cc < 32) ? smem[rr * 33 + cc]
                          : smem[2112 + rr * 33 + (cc - 32)];
        else
            v = (cc < 32) ? smem[2112 + cc * 33 + (rr - 32)]
                          : smem[1056 + (rr - 32) * 33 + (cc - 32)];
        outp[e] = v;
    }
}

// ---------------------------------------------------------------------------
// Kernel 2: sum partials per feature -> K[f], zero diagonal.
// Main path (singleF < 0): grid 448; A features have 128 partial rows at
// base f*128, B features 64 rows at base 384+(f-3)*64.
// Fallback (singleF >= 0): grid 64, base 0, count by feature type.
// ---------------------------------------------------------------------------
__global__ __launch_bounds__(256) void reduce_kernel(
    const float* __restrict__ partials, float* __restrict__ K, int singleF)
{
    __shared__ double red[256];
    int f, eblk, base, count;
    if (singleF < 0) {
        f = blockIdx.x >> 6; eblk = blockIdx.x & 63;
        if (f < 3) { base = f * 128;            count = 128; }
        else       { base = 384 + (f - 3) * 64; count = 64;  }
    } else {
        f = singleF; eblk = blockIdx.x; base = 0;
        count = (f < 3) ? 128 : 64;
    }
    const int e = (eblk << 6) + (threadIdx.x & 63);
    const int jg = threadIdx.x >> 6;

    double s0 = 0.0, s1 = 0.0;
    for (int j = jg; j < count; j += 8) {
        s0 += (double)partials[(size_t)(base + j) * PSTRIDE + e];
        s1 += (double)partials[(size_t)(base + j + 4) * PSTRIDE + e];
    }
    red[threadIdx.x] = s0 + s1;
    __syncthreads();
    if (jg == 0) {
        double tot = red[threadIdx.x] + red[threadIdx.x + 64]
                   + red[threadIdx.x + 128] + red[threadIdx.x + 192];
        int rr = e >> 6, cc = e & 63;
        K[f * 4096 + e] = (rr == cc) ? 0.f : (float)tot;
    }
}

// ---------------------------------------------------------------------------
// Kernel 3: one block per (i,j) pair -> unbiased HSIC in fp64.
// ---------------------------------------------------------------------------
__global__ __launch_bounds__(256) void hsic_kernel(
    const float* __restrict__ K, double* __restrict__ hsic_out)
{
    const int p = blockIdx.x;
    int i, j;
    if (p < 9) { i = p / 3; j = p % 3; }
    else       { int q = p - 9; i = 3 + q / 4; j = 3 + q % 4; }
    const float* Ki = K + i * 4096;
    const float* Kj = K + j * 4096;
    const int t = threadIdx.x;

    __shared__ double red[256];
    __shared__ double ri[64], rj[64];

    double local = 0.0;
    for (int e = t; e < 4096; e += 256)
        local += (double)Ki[e] * (double)Kj[e];
    red[t] = local; __syncthreads();
    for (int s = 128; s > 0; s >>= 1) {
        if (t < s) red[t] += red[t + s];
        __syncthreads();
    }

    if (t < 64) {
        double s = 0.0;
        for (int mc = 0; mc < 64; ++mc) s += (double)Ki[t * 64 + mc];
        ri[t] = s;
    } else if (t < 128) {
        int n = t - 64;
        double s = 0.0;
        for (int mc = 0; mc < 64; ++mc) s += (double)Kj[n * 64 + mc];
        rj[n] = s;
    }
    __syncthreads();

    if (t == 0) {
        double tr = red[0];
        double rr = 0.0, si = 0.0, sj = 0.0;
        for (int n = 0; n < 64; ++n) {
            rr += ri[n] * rj[n];
            si += ri[n];
            sj += rj[n];
        }
        const double N = 64.0;
        const double c1 = (N - 1.0) * (N - 2.0);
        const double c2 = N - 2.0;
        const double c3 = N * (N - 3.0);
        hsic_out[p] = (tr + si * sj / c1 - 2.0 * rr / c2) / c3;
    }
}

// ---------------------------------------------------------------------------
// Kernel 4: combine -> loss.
// ---------------------------------------------------------------------------
__global__ __launch_bounds__(64) void final_kernel(
    const double* __restrict__ hsic, const float* __restrict__ ce_rows,
    float* __restrict__ out_loss)
{
    if (threadIdx.x != 0) return;
    double ce = 0.0;
    for (int n = 0; n < 64; ++n) ce += (double)ce_rows[n];
    ce /= 64.0;

    double cka_total = 0.0;
    for (int i = 0; i < 3; ++i)
        for (int j = 0; j < 3; ++j)
            cka_total += hsic[i * 3 + j] / sqrt(hsic[i * 3 + i] * hsic[j * 3 + j]);
    for (int i = 0; i < 4; ++i)
        for (int j = 0; j < 4; ++j)
            cka_total += hsic[9 + i * 4 + j] / sqrt(hsic[9 + i * 4 + i] * hsic[9 + j * 4 + j]);

    out_loss[0] = (float)(ce + 0.1 * cka_total);
}

// ---------------------------------------------------------------------------
extern "C" void kernel_launch(void* const* d_in, const int* in_sizes, int n_in,
                              void* d_out, int out_size, void* d_ws, size_t ws_size,
                              hipStream_t stream)
{
    const float* output  = (const float*)d_in[0];
    const int*   target  = (const int*)d_in[1];
    const float* feats_a = (const float*)d_in[2];
    const float* feats_b = (const float*)d_in[3];
    float* out = (float*)d_out;

    char* ws = (char*)d_ws;
    float*  K        = (float*)ws;                 // 114688 B
    float*  ce_rows  = (float*)(ws + 114688);      // 256 B
    double* hsic     = (double*)(ws + 114944);     // 200 B
    float*  partials = (float*)(ws + 131072);

    const size_t partMain = (size_t)640 * PSTRIDE * 4;   // 10.65 MB
    const size_t mainNeed = 131072 + partMain;

    if (ws_size >= mainNeed) {
        // ---------------- one-shot path ----------------
        hipLaunchKernelGGL(gram_ce_kernel, dim3(640 + 64), dim3(512), 0, stream,
                           feats_a, feats_b, partials, 3, 4,
                           output, target, out + 1, ce_rows, 64);
        hipLaunchKernelGGL(reduce_kernel, dim3(448), dim3(256), 0, stream,
                           partials, K, -1);
    } else {
        // ---------------- per-feature fallback (~2.3 MB) ----------------
        for (int f = 0; f < 7; ++f) {
            if (f < 3) {
                const float* X = feats_a + (size_t)f * 64 * 65536;
                int ce = (f == 0) ? 64 : 0;
                hipLaunchKernelGGL(gram_ce_kernel, dim3(128 + ce), dim3(512), 0, stream,
                                   X, (const float*)nullptr, partials, 1, 0,
                                   output, target, out + 1, ce_rows, ce);
            } else {
                const float* X = feats_b + (size_t)(f - 3) * 64 * 32768;
                hipLaunchKernelGGL(gram_ce_kernel, dim3(64), dim3(512), 0, stream,
                                   (const float*)nullptr, X, partials, 0, 1,
                                   output, target, out + 1, ce_rows, 0);
            }
            hipLaunchKernelGGL(reduce_kernel, dim3(64), dim3(256), 0, stream,
                               partials, K, f);
        }
    }

    hipLaunchKernelGGL(hsic_kernel, dim3(25), dim3(256), 0, stream, K, hsic);
    hipLaunchKernelGGL(final_kernel, dim3(1), dim3(64), 0, stream,
                       hsic, ce_rows, out);
}

// Round 12
// 156.852 us; speedup vs baseline: 1.3430x; 1.3430x over previous
//
#include <hip/hip_runtime.h>
#include <math.h>

typedef __attribute__((ext_vector_type(8))) short short8;
typedef __attribute__((ext_vector_type(4))) float f32x4;
typedef __attribute__((ext_vector_type(16))) float f32x16;

#define PSTRIDE 4160          // partials row stride in floats (non-pow2)

// round-to-nearest-even fp32 -> bf16 bits (validated numerics, keep exact)
__device__ __forceinline__ unsigned int bf16_rn(float x) {
    unsigned int u = __float_as_uint(x);
    return (u + 0x7FFFu + ((u >> 16) & 1u)) >> 16;
}

__device__ __forceinline__ short8 cvt8(float4 a, float4 b) {
    short8 h;
    h[0] = (short)bf16_rn(a.x); h[1] = (short)bf16_rn(a.y);
    h[2] = (short)bf16_rn(a.z); h[3] = (short)bf16_rn(a.w);
    h[4] = (short)bf16_rn(b.x); h[5] = (short)bf16_rn(b.y);
    h[6] = (short)bf16_rn(b.z); h[7] = (short)bf16_rn(b.w);
    return h;
}

// ---------------------------------------------------------------------------
// Kernel 1 (gram + CE fused): 512 threads (8 waves).  [EXACT R4 REVERT]
// R4 measured: gram 50 us, end-to-end 158.4 us — the best of 12 rounds and
// the only config that reached the per-CU scattered-load miss-queue roofline
// (~19.2 GB/s/CU = ~64 outstanding 64B lines / ~210ns L3-hit latency).
// Traffic-reducing restructures (R5-R11: symmetric 3-acc, DMA staging, asm
// batching) all lost the queue-filling codegen (deep unrolled loops x 22
// waves/CU) and regressed. Structure: one block per (feature, 512-k chunk);
// wave = (khalf h, quadrant q); each wave computes its 32x32 quadrant over a
// 256-k window with mfma_f32_32x32x16_bf16, fragments loaded directly from
// global fp32 (float4 pairs, 16 fully-unrolled iterations) and converted
// in-register. k-half pairs reduce via LDS; 64x64 partials write.
// ---------------------------------------------------------------------------
__global__ __launch_bounds__(512, 6) void gram_ce_kernel(
    const float* __restrict__ A, const float* __restrict__ B,
    float* __restrict__ partials, int nfA, int nfB,
    const float* __restrict__ logits, const int* __restrict__ target,
    float* __restrict__ out_copy, float* __restrict__ ce_rows, int ceCount)
{
    __shared__ float smem[4096];   // gram: 4x[32][32] quadrant buf; CE: red
    const int t = threadIdx.x;

    if ((int)blockIdx.x < ceCount) {
        // ------------------ CE block ------------------
        const int row = blockIdx.x;
        const float* x = logits + row * 1000;
        float m = -INFINITY;
        for (int i = t; i < 1000; i += 512) {
            float v = x[i];
            out_copy[row * 1000 + i] = v;
            m = fmaxf(m, v);
        }
        smem[t] = m; __syncthreads();
        for (int s = 256; s > 0; s >>= 1) {
            if (t < s) smem[t] = fmaxf(smem[t], smem[t + s]);
            __syncthreads();
        }
        m = smem[0];
        __syncthreads();
        float ssum = 0.f;
        for (int i = t; i < 1000; i += 512) ssum += expf(x[i] - m);
        smem[t] = ssum; __syncthreads();
        for (int s = 256; s > 0; s >>= 1) {
            if (t < s) smem[t] += smem[t + s];
            __syncthreads();
        }
        if (t == 0) {
            double lse = (double)m + log((double)smem[0]);
            int tg = target[row];
            ce_rows[row] = (float)(-((double)x[tg] - lse));
        }
        return;
    }

    // ------------------ gram block ------------------
    const int gb = blockIdx.x - ceCount;
    const int uA = nfA * 128;              // A chunk-blocks (128 x 512k /feat)
    const float* xf;
    int c, D;
    if (gb < uA) {
        int f = gb >> 7; c = gb & 127; D = 65536;
        xf = A + (size_t)f * 64 * 65536;
    } else {
        int v = gb - uA;
        int f = v >> 6; c = v & 63; D = 32768;
        xf = B + (size_t)f * 64 * 32768;
    }

    const int wave = t >> 6, lane = t & 63;
    const int q = wave & 3, h = wave >> 2;
    const int wr = q >> 1, wc = q & 1;
    const int lr = lane & 31, hi = lane >> 5;
    const int k0 = c * 512 + h * 256 + hi * 8;

    const float* pA = xf + (size_t)(wr * 32 + lr) * D + k0;
    const float* pB = xf + (size_t)(wc * 32 + lr) * D + k0;

    f32x16 acc = (f32x16)0.f;
    if (wr == wc) {
#pragma unroll
        for (int s = 0; s < 16; ++s) {
            float4 a0 = *(const float4*)(pA + s * 16);
            float4 a1 = *(const float4*)(pA + s * 16 + 4);
            short8 fa = cvt8(a0, a1);
            acc = __builtin_amdgcn_mfma_f32_32x32x16_bf16(fa, fa, acc, 0, 0, 0);
        }
    } else {
#pragma unroll
        for (int s = 0; s < 16; ++s) {
            float4 a0 = *(const float4*)(pA + s * 16);
            float4 a1 = *(const float4*)(pA + s * 16 + 4);
            float4 b0 = *(const float4*)(pB + s * 16);
            float4 b1 = *(const float4*)(pB + s * 16 + 4);
            short8 fa = cvt8(a0, a1);
            short8 fb = cvt8(b0, b1);
            acc = __builtin_amdgcn_mfma_f32_32x32x16_bf16(fa, fb, acc, 0, 0, 0);
        }
    }

    // ---- k-half pair reduce via LDS (C layout: col=lane&31,
    //      row=(r&3)+8*(r>>2)+4*(lane>>5), verified m74/m101) ----
    float* qb = smem + q * 1024;
    if (h == 0) {
#pragma unroll
        for (int r = 0; r < 16; ++r) {
            int rl = (r & 3) + 8 * (r >> 2) + 4 * hi;
            qb[rl * 32 + lr] = acc[r];
        }
    }
    __syncthreads();
    if (h == 1) {
#pragma unroll
        for (int r = 0; r < 16; ++r) {
            int rl = (r & 3) + 8 * (r >> 2) + 4 * hi;
            qb[rl * 32 + lr] += acc[r];
        }
    }
    __syncthreads();

    // ---- remap [q][32][32] -> [64][64], write partials (float4) ----
    float* outp = partials + (size_t)gb * PSTRIDE;
    const f32x4* s4 = (const f32x4*)smem;
    f32x4* o4 = (f32x4*)outp;
    for (int e = t; e < 1024; e += 512) {
        int qq = e >> 8, rl = (e >> 3) & 31, cl = e & 7;
        o4[((qq >> 1) * 32 + rl) * 16 + (qq & 1) * 8 + cl] = s4[e];
    }
}

// ---------------------------------------------------------------------------
// Kernel 2: sum partials per feature -> K[f], zero diagonal.
// Main path (singleF < 0): grid 448; A features have 128 partial rows at
// base f*128, B features 64 rows at base 384+(f-3)*64.
// Fallback (singleF >= 0): grid 64, base 0, count by feature type.
// ---------------------------------------------------------------------------
__global__ __launch_bounds__(256) void reduce_kernel(
    const float* __restrict__ partials, float* __restrict__ K, int singleF)
{
    __shared__ double red[256];
    int f, eblk, base, count;
    if (singleF < 0) {
        f = blockIdx.x >> 6; eblk = blockIdx.x & 63;
        if (f < 3) { base = f * 128;            count = 128; }
        else       { base = 384 + (f - 3) * 64; count = 64;  }
    } else {
        f = singleF; eblk = blockIdx.x; base = 0;
        count = (f < 3) ? 128 : 64;
    }
    const int e = (eblk << 6) + (threadIdx.x & 63);
    const int jg = threadIdx.x >> 6;

    double s0 = 0.0, s1 = 0.0;
    for (int j = jg; j < count; j += 8) {
        s0 += (double)partials[(size_t)(base + j) * PSTRIDE + e];
        s1 += (double)partials[(size_t)(base + j + 4) * PSTRIDE + e];
    }
    red[threadIdx.x] = s0 + s1;
    __syncthreads();
    if (jg == 0) {
        double tot = red[threadIdx.x] + red[threadIdx.x + 64]
                   + red[threadIdx.x + 128] + red[threadIdx.x + 192];
        int rr = e >> 6, cc = e & 63;
        K[f * 4096 + e] = (rr == cc) ? 0.f : (float)tot;
    }
}

// ---------------------------------------------------------------------------
// Kernel 3: one block per (i,j) pair -> unbiased HSIC in fp64.
// ---------------------------------------------------------------------------
__global__ __launch_bounds__(256) void hsic_kernel(
    const float* __restrict__ K, double* __restrict__ hsic_out)
{
    const int p = blockIdx.x;
    int i, j;
    if (p < 9) { i = p / 3; j = p % 3; }
    else       { int q = p - 9; i = 3 + q / 4; j = 3 + q % 4; }
    const float* Ki = K + i * 4096;
    const float* Kj = K + j * 4096;
    const int t = threadIdx.x;

    __shared__ double red[256];
    __shared__ double ri[64], rj[64];

    double local = 0.0;
    for (int e = t; e < 4096; e += 256)
        local += (double)Ki[e] * (double)Kj[e];
    red[t] = local; __syncthreads();
    for (int s = 128; s > 0; s >>= 1) {
        if (t < s) red[t] += red[t + s];
        __syncthreads();
    }

    if (t < 64) {
        double s = 0.0;
        for (int mc = 0; mc < 64; ++mc) s += (double)Ki[t * 64 + mc];
        ri[t] = s;
    } else if (t < 128) {
        int n = t - 64;
        double s = 0.0;
        for (int mc = 0; mc < 64; ++mc) s += (double)Kj[n * 64 + mc];
        rj[n] = s;
    }
    __syncthreads();

    if (t == 0) {
        double tr = red[0];
        double rr = 0.0, si = 0.0, sj = 0.0;
        for (int n = 0; n < 64; ++n) {
            rr += ri[n] * rj[n];
            si += ri[n];
            sj += rj[n];
        }
        const double N = 64.0;
        const double c1 = (N - 1.0) * (N - 2.0);
        const double c2 = N - 2.0;
        const double c3 = N * (N - 3.0);
        hsic_out[p] = (tr + si * sj / c1 - 2.0 * rr / c2) / c3;
    }
}

// ---------------------------------------------------------------------------
// Kernel 4: combine -> loss.
// ---------------------------------------------------------------------------
__global__ __launch_bounds__(64) void final_kernel(
    const double* __restrict__ hsic, const float* __restrict__ ce_rows,
    float* __restrict__ out_loss)
{
    if (threadIdx.x != 0) return;
    double ce = 0.0;
    for (int n = 0; n < 64; ++n) ce += (double)ce_rows[n];
    ce /= 64.0;

    double cka_total = 0.0;
    for (int i = 0; i < 3; ++i)
        for (int j = 0; j < 3; ++j)
            cka_total += hsic[i * 3 + j] / sqrt(hsic[i * 3 + i] * hsic[j * 3 + j]);
    for (int i = 0; i < 4; ++i)
        for (int j = 0; j < 4; ++j)
            cka_total += hsic[9 + i * 4 + j] / sqrt(hsic[9 + i * 4 + i] * hsic[9 + j * 4 + j]);

    out_loss[0] = (float)(ce + 0.1 * cka_total);
}

// ---------------------------------------------------------------------------
extern "C" void kernel_launch(void* const* d_in, const int* in_sizes, int n_in,
                              void* d_out, int out_size, void* d_ws, size_t ws_size,
                              hipStream_t stream)
{
    const float* output  = (const float*)d_in[0];
    const int*   target  = (const int*)d_in[1];
    const float* feats_a = (const float*)d_in[2];
    const float* feats_b = (const float*)d_in[3];
    float* out = (float*)d_out;

    char* ws = (char*)d_ws;
    float*  K        = (float*)ws;                 // 114688 B
    float*  ce_rows  = (float*)(ws + 114688);      // 256 B
    double* hsic     = (double*)(ws + 114944);     // 200 B
    float*  partials = (float*)(ws + 131072);

    const size_t partMain = (size_t)640 * PSTRIDE * 4;   // 10.65 MB
    const size_t mainNeed = 131072 + partMain;

    if (ws_size >= mainNeed) {
        // ---------------- one-shot path ----------------
        hipLaunchKernelGGL(gram_ce_kernel, dim3(640 + 64), dim3(512), 0, stream,
                           feats_a, feats_b, partials, 3, 4,
                           output, target, out + 1, ce_rows, 64);
        hipLaunchKernelGGL(reduce_kernel, dim3(448), dim3(256), 0, stream,
                           partials, K, -1);
    } else {
        // ---------------- per-feature fallback (~2.3 MB) ----------------
        for (int f = 0; f < 7; ++f) {
            if (f < 3) {
                const float* X = feats_a + (size_t)f * 64 * 65536;
                int ce = (f == 0) ? 64 : 0;
                hipLaunchKernelGGL(gram_ce_kernel, dim3(128 + ce), dim3(512), 0, stream,
                                   X, (const float*)nullptr, partials, 1, 0,
                                   output, target, out + 1, ce_rows, ce);
            } else {
                const float* X = feats_b + (size_t)(f - 3) * 64 * 32768;
                hipLaunchKernelGGL(gram_ce_kernel, dim3(64), dim3(512), 0, stream,
                                   (const float*)nullptr, X, partials, 0, 1,
                                   output, target, out + 1, ce_rows, 0);
            }
            hipLaunchKernelGGL(reduce_kernel, dim3(64), dim3(256), 0, stream,
                               partials, K, f);
        }
    }

    hipLaunchKernelGGL(hsic_kernel, dim3(25), dim3(256), 0, stream, K, hsic);
    hipLaunchKernelGGL(final_kernel, dim3(1), dim3(64), 0, stream,
                       hsic, ce_rows, out);
}